// Round 1
// 827.698 us; speedup vs baseline: 1.2680x; 1.2680x over previous
//
#include <hip/hip_runtime.h>
#include <hip/hip_bf16.h>

#define B_  2
#define S_  2048
#define H_  1024
#define NH_ 16
#define HD_ 64

typedef __bf16 bf16_t;
typedef __attribute__((ext_vector_type(4))) __bf16 bf16x4;
typedef __attribute__((ext_vector_type(8))) __bf16 bf16x8;
typedef __attribute__((ext_vector_type(4))) float f32x4;

__device__ __forceinline__ void gld_lds16(const bf16_t* g, bf16_t* l) {
    __builtin_amdgcn_global_load_lds(
        (const __attribute__((address_space(1))) unsigned int*)g,
        (__attribute__((address_space(3))) unsigned int*)l, 16, 0, 0);
}

// ---------------------------------------------------------------------------
// Kernel 0: cast X and Wq/Wk/Wv to bf16 once (fp32 GEMM inputs were 2x the
// traffic and forced VALU cvt in the GEMM staging path).
// 4 floats/thread, exact-size grid (7340032/4/256 = 7168 blocks).
// ---------------------------------------------------------------------------
__global__ __launch_bounds__(256) void cast_bf16(
    const float* __restrict__ X, const float* __restrict__ Wq,
    const float* __restrict__ Wk, const float* __restrict__ Wv,
    bf16_t* __restrict__ Xb, bf16_t* __restrict__ Wb)
{
    const size_t XN = (size_t)B_ * S_ * H_;           // 4,194,304
    size_t i4 = ((size_t)blockIdx.x * 256 + threadIdx.x) * 4;
    const float* src;
    bf16_t* dst;
    if (i4 < XN) {
        src = X + i4; dst = Xb + i4;
    } else {
        size_t j = i4 - XN;                           // [0, 3M)
        int wsel = (int)(j >> 20);                    // 1M floats per W
        const float* Wp = wsel == 0 ? Wq : (wsel == 1 ? Wk : Wv);
        src = Wp + (j & 1048575); dst = Wb + j;
    }
    float4 v = *(const float4*)src;
    bf16x4 o = { (bf16_t)v.x, (bf16_t)v.y, (bf16_t)v.z, (bf16_t)v.w };
    *(bf16x4*)dst = o;
}

// ---------------------------------------------------------------------------
// Kernel 1: QKV projection, m97 structure: 128x128 tile, BK=64, 4 waves
// (2x2), 4x4 16x16x32 fragments per wave, global_load_lds width=16,
// linear LDS (T2 swizzle is null at 128^2+2-phase per regime gate).
// q pre-scaled by 1/sqrt(HD)=0.125. Output scattered to [B][NH][S][HD] bf16.
// ---------------------------------------------------------------------------
__global__ __launch_bounds__(256) void qkv_gemm(
    const bf16_t* __restrict__ Xb, const bf16_t* __restrict__ Wb,
    const float* __restrict__ bq, const float* __restrict__ bk,
    const float* __restrict__ bv,
    bf16_t* __restrict__ qbuf, bf16_t* __restrict__ kbuf, bf16_t* __restrict__ vbuf)
{
    const int which = blockIdx.z;
    const bf16_t* W  = Wb + (size_t)which * H_ * H_;
    const float* bias = which == 0 ? bq : (which == 1 ? bk : bv);
    bf16_t* out       = which == 0 ? qbuf : (which == 1 ? kbuf : vbuf);
    const float scale = which == 0 ? 0.125f : 1.0f;

    const int m0 = blockIdx.x * 128;   // rows of X (0..4096)
    const int n0 = blockIdx.y * 128;   // rows of W = output cols (0..1024)
    const int t    = threadIdx.x;
    const int lane = t & 63;
    const int w    = t >> 6;
    const int wr   = w >> 1, wc = w & 1;
    const int lo   = lane & 15, g = lane >> 4;

    __shared__ bf16_t As[128 * 64];
    __shared__ bf16_t Bs[128 * 64];

    // global_load_lds mapping: instr p stages rows [p*32, p*32+32); within a
    // wave, LDS dest = (p*2048 + w*512)*2B + lane*16B -> global row
    // m0 + p*32 + w*8 + lane/8, col (lane&7)*8 (16B contiguous along K).
    const int srow = w * 8 + (lane >> 3);
    const int scol = (lane & 7) * 8;
    const bf16_t* ga = Xb + (size_t)(m0 + srow) * H_ + scol;
    const bf16_t* gb = W  + (size_t)(n0 + srow) * H_ + scol;

    f32x4 acc[4][4];
#pragma unroll
    for (int mt = 0; mt < 4; ++mt)
#pragma unroll
        for (int nt = 0; nt < 4; ++nt)
            acc[mt][nt] = (f32x4){0.f, 0.f, 0.f, 0.f};

    for (int kc = 0; kc < 16; ++kc) {
#pragma unroll
        for (int p = 0; p < 4; ++p) {
            gld_lds16(ga + (size_t)p * 32 * H_ + kc * 64, &As[p * 2048 + w * 512]);
            gld_lds16(gb + (size_t)p * 32 * H_ + kc * 64, &Bs[p * 2048 + w * 512]);
        }
        __syncthreads();

        bf16x8 a0[4], a1[4];
#pragma unroll
        for (int mt = 0; mt < 4; ++mt) {
            a0[mt] = *(const bf16x8*)&As[(wr * 64 + mt * 16 + lo) * 64 + g * 8];
            a1[mt] = *(const bf16x8*)&As[(wr * 64 + mt * 16 + lo) * 64 + g * 8 + 32];
        }
#pragma unroll
        for (int nt = 0; nt < 4; ++nt) {
            bf16x8 b0 = *(const bf16x8*)&Bs[(wc * 64 + nt * 16 + lo) * 64 + g * 8];
            bf16x8 b1 = *(const bf16x8*)&Bs[(wc * 64 + nt * 16 + lo) * 64 + g * 8 + 32];
#pragma unroll
            for (int mt = 0; mt < 4; ++mt) {
                acc[mt][nt] = __builtin_amdgcn_mfma_f32_16x16x32_bf16(a0[mt], b0, acc[mt][nt], 0, 0, 0);
                acc[mt][nt] = __builtin_amdgcn_mfma_f32_16x16x32_bf16(a1[mt], b1, acc[mt][nt], 0, 0, 0);
            }
        }
        __syncthreads();
    }

    // epilogue: +bias, *scale, cast bf16, scatter to [B][NH][S][HD]
#pragma unroll
    for (int nt = 0; nt < 4; ++nt) {
        int n  = n0 + wc * 64 + nt * 16 + lo;
        int hh = n >> 6, d = n & 63;
        float bv_ = bias[n];
#pragma unroll
        for (int mt = 0; mt < 4; ++mt) {
#pragma unroll
            for (int r = 0; r < 4; ++r) {
                int m = m0 + wr * 64 + mt * 16 + g * 4 + r;  // row=(lane>>4)*4+reg
                int b = m >> 11, s = m & 2047;
                out[(((size_t)(b * NH_ + hh) * S_) + s) * HD_ + d] =
                    (bf16_t)((acc[mt][nt][r] + bv_) * scale);
            }
        }
    }
}

// ---------------------------------------------------------------------------
// Kernel 2: flash-style attention. Changes vs prior version:
//  - rel_pos double-buffer prefetch in registers (hide ~900cy HBM latency
//    under softmax+PV+staging)
//  - V^T stage XOR-swizzled (s' = row ^ c8): write side conflict-free
//    (was 16-way), read side stays contiguous bf16x8 / balanced banks
//  - P store XOR-swizzled (col ^ 8g): conflict-free (was 2-way)
//  - P strip aliased onto dead Q tile: LDS 36.9KB -> 27.6KB (5 blocks/CU)
//  - mid-loop barrier removed (P is wave-private; lgkmcnt orders in-wave)
// ---------------------------------------------------------------------------
__global__ __launch_bounds__(256, 4) void attn(
    const bf16_t* __restrict__ qbuf, const bf16_t* __restrict__ kbuf,
    const bf16_t* __restrict__ vbuf,
    const float* __restrict__ mask, const float* __restrict__ rel,
    float* __restrict__ out)
{
    const int b = blockIdx.z, h = blockIdx.y, q0 = blockIdx.x * 64;
    const int t    = threadIdx.x;
    const int lane = t & 63;
    const int w    = t >> 6;
    const int lo   = lane & 15;
    const int g    = lane >> 4;

    __shared__ bf16_t QPs[64 * 72];   // Q tile; re-used as per-wave P strips
    __shared__ bf16_t Ks[64 * 72];
    __shared__ bf16_t VTs[64 * 72];   // V^T, XOR-swizzled

    const bf16_t* qg = qbuf + ((size_t)(b * NH_ + h) * S_ + q0) * HD_;
    const bf16_t* kg = kbuf + (size_t)(b * NH_ + h) * S_ * HD_;
    const bf16_t* vg = vbuf + (size_t)(b * NH_ + h) * S_ * HD_;
    const float*  relg  = rel + ((size_t)((b * NH_ + h) * S_ + q0)) * S_;
    const float*  maskg = mask + b * S_;

    // stage Q tile
#pragma unroll
    for (int p = 0; p < 2; ++p) {
        int idx = t + p * 256;
        int row = idx >> 3, c8 = (idx & 7) * 8;
        *(uint4*)&QPs[row * 72 + c8] = *(const uint4*)&qg[row * 64 + c8];
    }
    __syncthreads();

    // Q A-frags (q pre-scaled by 1/8 in the GEMM)
    bf16x8 aq0 = *(const bf16x8*)&QPs[(w * 16 + lo) * 72 + g * 8];
    bf16x8 aq1 = *(const bf16x8*)&QPs[(w * 16 + lo) * 72 + g * 8 + 32];
    // NOTE: all waves' aq reads are drained at the first in-loop barrier
    // (s_waitcnt before s_barrier), so P writes into QPs afterward are safe.

    float mi[4], li[4];
    f32x4 accO[4];
#pragma unroll
    for (int r = 0; r < 4; ++r) { mi[r] = -1e30f; li[r] = 0.f; }
#pragma unroll
    for (int dt = 0; dt < 4; ++dt) accO[dt] = (f32x4){0.f, 0.f, 0.f, 0.f};

    const int qrow = w * 16 + g * 4;  // +r

    // prefetch rel for chunk 0
    float rl[4][4];
#pragma unroll
    for (int r = 0; r < 4; ++r)
#pragma unroll
        for (int nt = 0; nt < 4; ++nt)
            rl[r][nt] = relg[(size_t)(qrow + r) * S_ + nt * 16 + lo];

    for (int kc = 0; kc < 32; ++kc) {
        // stage K (native) and V^T (swizzled: element (s,d) at VTs[d*72 + (s^c8)])
#pragma unroll
        for (int p = 0; p < 2; ++p) {
            int idx = t + p * 256;
            int row = idx >> 3, c8 = (idx & 7) * 8;
            *(uint4*)&Ks[row * 72 + c8] = *(const uint4*)&kg[(size_t)(kc * 64 + row) * 64 + c8];
            uint4 vv = *(const uint4*)&vg[(size_t)(kc * 64 + row) * 64 + c8];
            const bf16_t* vvp = (const bf16_t*)&vv;
            int sw = row ^ c8;        // c8 = ((d>>3)&7)<<3 for d in [c8, c8+8)
#pragma unroll
            for (int j = 0; j < 8; ++j) VTs[(c8 + j) * 72 + sw] = vvp[j];
        }
        __syncthreads();

        // QK^T: 16x64 strip per wave
        f32x4 sc[4];
#pragma unroll
        for (int nt = 0; nt < 4; ++nt) {
            bf16x8 b0 = *(const bf16x8*)&Ks[(nt * 16 + lo) * 72 + g * 8];
            bf16x8 b1 = *(const bf16x8*)&Ks[(nt * 16 + lo) * 72 + g * 8 + 32];
            f32x4 z = (f32x4){0.f, 0.f, 0.f, 0.f};
            z = __builtin_amdgcn_mfma_f32_16x16x32_bf16(aq0, b0, z, 0, 0, 0);
            z = __builtin_amdgcn_mfma_f32_16x16x32_bf16(aq1, b1, z, 0, 0, 0);
            sc[nt] = z;
        }

        // scores = qk + mask + rel (prefetched)
        float sv[4][4];
#pragma unroll
        for (int nt = 0; nt < 4; ++nt) {
            float mk = maskg[kc * 64 + nt * 16 + lo];
#pragma unroll
            for (int r = 0; r < 4; ++r)
                sv[r][nt] = sc[nt][r] + mk + rl[r][nt];
        }

        // issue next chunk's rel loads now; softmax+PV+stage hide the latency
        if (kc < 31) {
#pragma unroll
            for (int r = 0; r < 4; ++r)
#pragma unroll
                for (int nt = 0; nt < 4; ++nt)
                    rl[r][nt] = relg[(size_t)(qrow + r) * S_ + (kc + 1) * 64 + nt * 16 + lo];
        }

        // online softmax; P into this wave's swizzled strip (col ^ 8g, key=row>>2)
        bf16_t* Pw = &QPs[w * 16 * 72];
#pragma unroll
        for (int r = 0; r < 4; ++r) {
            float vmax = fmaxf(fmaxf(sv[r][0], sv[r][1]), fmaxf(sv[r][2], sv[r][3]));
#pragma unroll
            for (int mk2 = 1; mk2 < 16; mk2 <<= 1)
                vmax = fmaxf(vmax, __shfl_xor(vmax, mk2, 16));
            float mnew  = fmaxf(mi[r], vmax);
            float alpha = __expf(mi[r] - mnew);
            float rsum = 0.f;
#pragma unroll
            for (int nt = 0; nt < 4; ++nt) {
                float p = __expf(sv[r][nt] - mnew);
                sv[r][nt] = p;
                rsum += p;
            }
#pragma unroll
            for (int mk2 = 1; mk2 < 16; mk2 <<= 1)
                rsum += __shfl_xor(rsum, mk2, 16);
            li[r] = li[r] * alpha + rsum;
            mi[r] = mnew;
#pragma unroll
            for (int dt = 0; dt < 4; ++dt) accO[dt][r] *= alpha;
#pragma unroll
            for (int nt = 0; nt < 4; ++nt)
                Pw[(g * 4 + r) * 72 + ((nt * 16 + lo) ^ (g * 8))] = (bf16_t)sv[r][nt];
        }
        // no barrier: P strip is wave-private (in-wave ds ordering via lgkmcnt),
        // VTs/Ks stable since the stage barrier.

        // PV: P(16x64) * V-chunk(64x64)
        bf16x8 pa0 = *(const bf16x8*)&Pw[lo * 72 + ((g * 8)       ^ ((lo >> 2) * 8))];
        bf16x8 pa1 = *(const bf16x8*)&Pw[lo * 72 + (((4 + g) * 8) ^ ((lo >> 2) * 8))];
#pragma unroll
        for (int dt = 0; dt < 4; ++dt) {
            int d = dt * 16 + lo;
            bf16x8 v0 = *(const bf16x8*)&VTs[d * 72 + ((g * 8)       ^ (d & 56))];
            bf16x8 v1 = *(const bf16x8*)&VTs[d * 72 + (((4 + g) * 8) ^ (d & 56))];
            accO[dt] = __builtin_amdgcn_mfma_f32_16x16x32_bf16(pa0, v0, accO[dt], 0, 0, 0);
            accO[dt] = __builtin_amdgcn_mfma_f32_16x16x32_bf16(pa1, v1, accO[dt], 0, 0, 0);
        }
        __syncthreads();   // protect Ks/VTs before next stage
    }

    // epilogue: out[b][s][h*64+d] = O / l
#pragma unroll
    for (int dt = 0; dt < 4; ++dt) {
        int d = dt * 16 + lo;
#pragma unroll
        for (int r = 0; r < 4; ++r) {
            int row = q0 + w * 16 + g * 4 + r;
            out[((size_t)(b * S_ + row)) * H_ + h * HD_ + d] = accO[dt][r] / li[r];
        }
    }
}

extern "C" void kernel_launch(void* const* d_in, const int* in_sizes, int n_in,
                              void* d_out, int out_size, void* d_ws, size_t ws_size,
                              hipStream_t stream) {
    const float* hs   = (const float*)d_in[0];
    const float* mask = (const float*)d_in[1];
    const float* rel  = (const float*)d_in[2];
    const float* Wq   = (const float*)d_in[3];
    const float* bq   = (const float*)d_in[4];
    const float* Wk   = (const float*)d_in[5];
    const float* bk   = (const float*)d_in[6];
    const float* Wv   = (const float*)d_in[7];
    const float* bv   = (const float*)d_in[8];
    float* out = (float*)d_out;

    const size_t qkv_elems = (size_t)B_ * NH_ * S_ * HD_;  // 4,194,304
    bf16_t* qbuf = (bf16_t*)d_ws;
    bf16_t* kbuf = qbuf + qkv_elems;
    bf16_t* vbuf = kbuf + qkv_elems;
    bf16_t* Xb   = vbuf + qkv_elems;               // 4M elems
    bf16_t* Wb   = Xb   + qkv_elems;               // 3M elems (Wq,Wk,Wv)

    cast_bf16<<<7168, 256, 0, stream>>>(hs, Wq, Wk, Wv, Xb, Wb);
    qkv_gemm<<<dim3(32, 8, 3), 256, 0, stream>>>(Xb, Wb, bq, bk, bv,
                                                 qbuf, kbuf, vbuf);
    attn<<<dim3(S_ / 64, NH_, B_), 256, 0, stream>>>(qbuf, kbuf, vbuf, mask, rel, out);
}

// Round 2
// 795.701 us; speedup vs baseline: 1.3190x; 1.0402x over previous
//
#include <hip/hip_runtime.h>
#include <hip/hip_bf16.h>

#define B_  2
#define S_  2048
#define H_  1024
#define NH_ 16
#define HD_ 64

typedef __bf16 bf16_t;
typedef __attribute__((ext_vector_type(4))) __bf16 bf16x4;
typedef __attribute__((ext_vector_type(8))) __bf16 bf16x8;
typedef __attribute__((ext_vector_type(4))) float f32x4;

__device__ __forceinline__ void gld_lds16(const bf16_t* g, bf16_t* l) {
    __builtin_amdgcn_global_load_lds(
        (const __attribute__((address_space(1))) unsigned int*)g,
        (__attribute__((address_space(3))) unsigned int*)l, 16, 0, 0);
}

// ---------------------------------------------------------------------------
// Kernel 0: cast X and Wq/Wk/Wv to bf16 once.
// ---------------------------------------------------------------------------
__global__ __launch_bounds__(256) void cast_bf16(
    const float* __restrict__ X, const float* __restrict__ Wq,
    const float* __restrict__ Wk, const float* __restrict__ Wv,
    bf16_t* __restrict__ Xb, bf16_t* __restrict__ Wb)
{
    const size_t XN = (size_t)B_ * S_ * H_;           // 4,194,304
    size_t i4 = ((size_t)blockIdx.x * 256 + threadIdx.x) * 4;
    const float* src;
    bf16_t* dst;
    if (i4 < XN) {
        src = X + i4; dst = Xb + i4;
    } else {
        size_t j = i4 - XN;                           // [0, 3M)
        int wsel = (int)(j >> 20);                    // 1M floats per W
        const float* Wp = wsel == 0 ? Wq : (wsel == 1 ? Wk : Wv);
        src = Wp + (j & 1048575); dst = Wb + j;
    }
    float4 v = *(const float4*)src;
    bf16x4 o = { (bf16_t)v.x, (bf16_t)v.y, (bf16_t)v.z, (bf16_t)v.w };
    *(bf16x4*)dst = o;
}

// ---------------------------------------------------------------------------
// Kernel 1: QKV projection, m97 structure (unchanged from round 1; ~40-60us
// by FLOP/BW arithmetic, not the bottleneck).
// ---------------------------------------------------------------------------
__global__ __launch_bounds__(256) void qkv_gemm(
    const bf16_t* __restrict__ Xb, const bf16_t* __restrict__ Wb,
    const float* __restrict__ bq, const float* __restrict__ bk,
    const float* __restrict__ bv,
    bf16_t* __restrict__ qbuf, bf16_t* __restrict__ kbuf, bf16_t* __restrict__ vbuf)
{
    const int which = blockIdx.z;
    const bf16_t* W  = Wb + (size_t)which * H_ * H_;
    const float* bias = which == 0 ? bq : (which == 1 ? bk : bv);
    bf16_t* out       = which == 0 ? qbuf : (which == 1 ? kbuf : vbuf);
    const float scale = which == 0 ? 0.125f : 1.0f;

    const int m0 = blockIdx.x * 128;
    const int n0 = blockIdx.y * 128;
    const int t    = threadIdx.x;
    const int lane = t & 63;
    const int w    = t >> 6;
    const int wr   = w >> 1, wc = w & 1;
    const int lo   = lane & 15, g = lane >> 4;

    __shared__ bf16_t As[128 * 64];
    __shared__ bf16_t Bs[128 * 64];

    const int srow = w * 8 + (lane >> 3);
    const int scol = (lane & 7) * 8;
    const bf16_t* ga = Xb + (size_t)(m0 + srow) * H_ + scol;
    const bf16_t* gb = W  + (size_t)(n0 + srow) * H_ + scol;

    f32x4 acc[4][4];
#pragma unroll
    for (int mt = 0; mt < 4; ++mt)
#pragma unroll
        for (int nt = 0; nt < 4; ++nt)
            acc[mt][nt] = (f32x4){0.f, 0.f, 0.f, 0.f};

    for (int kc = 0; kc < 16; ++kc) {
#pragma unroll
        for (int p = 0; p < 4; ++p) {
            gld_lds16(ga + (size_t)p * 32 * H_ + kc * 64, &As[p * 2048 + w * 512]);
            gld_lds16(gb + (size_t)p * 32 * H_ + kc * 64, &Bs[p * 2048 + w * 512]);
        }
        __syncthreads();

        bf16x8 a0[4], a1[4];
#pragma unroll
        for (int mt = 0; mt < 4; ++mt) {
            a0[mt] = *(const bf16x8*)&As[(wr * 64 + mt * 16 + lo) * 64 + g * 8];
            a1[mt] = *(const bf16x8*)&As[(wr * 64 + mt * 16 + lo) * 64 + g * 8 + 32];
        }
#pragma unroll
        for (int nt = 0; nt < 4; ++nt) {
            bf16x8 b0 = *(const bf16x8*)&Bs[(wc * 64 + nt * 16 + lo) * 64 + g * 8];
            bf16x8 b1 = *(const bf16x8*)&Bs[(wc * 64 + nt * 16 + lo) * 64 + g * 8 + 32];
#pragma unroll
            for (int mt = 0; mt < 4; ++mt) {
                acc[mt][nt] = __builtin_amdgcn_mfma_f32_16x16x32_bf16(a0[mt], b0, acc[mt][nt], 0, 0, 0);
                acc[mt][nt] = __builtin_amdgcn_mfma_f32_16x16x32_bf16(a1[mt], b1, acc[mt][nt], 0, 0, 0);
            }
        }
        __syncthreads();
    }

#pragma unroll
    for (int nt = 0; nt < 4; ++nt) {
        int n  = n0 + wc * 64 + nt * 16 + lo;
        int hh = n >> 6, d = n & 63;
        float bv_ = bias[n];
#pragma unroll
        for (int mt = 0; mt < 4; ++mt) {
#pragma unroll
            for (int r = 0; r < 4; ++r) {
                int m = m0 + wr * 64 + mt * 16 + g * 4 + r;
                int b = m >> 11, s = m & 2047;
                out[(((size_t)(b * NH_ + hh) * S_) + s) * HD_ + d] =
                    (bf16_t)((acc[mt][nt][r] + bv_) * scale);
            }
        }
    }
}

// ---------------------------------------------------------------------------
// Kernel 2: flash attention, pipelined. Changes vs round 1:
//  - raw s_barrier + explicit lgkmcnt(0) instead of __syncthreads():
//    __syncthreads emits s_waitcnt vmcnt(0) which drained every prefetched
//    load at the barrier and defeated the pipeline. Now kv/rel loads stay
//    in flight across barriers (counted vmcnt at consume points).
//  - K/V staged global->reg->LDS with next-chunk loads issued at the write
//    phase (T14 async-stage split; one full chunk of compute hides latency).
//  - mask staged to LDS once: per-chunk VMEM = exactly {4 kv, 16 rel} loads.
//  - XCD swizzle: each XCD gets 4 (b,h) x 32 q-tiles -> K/V L2-resident.
//  - s_setprio(1) around MFMA clusters (T5).
//  - launch_bounds(256,3): cap 170 VGPR (no spill risk), LDS 35.8KB.
// ---------------------------------------------------------------------------
__global__ __launch_bounds__(256, 3) void attn(
    const bf16_t* __restrict__ qbuf, const bf16_t* __restrict__ kbuf,
    const bf16_t* __restrict__ vbuf,
    const float* __restrict__ mask, const float* __restrict__ rel,
    float* __restrict__ out)
{
    // XCD-aware decode: hw bid round-robins XCDs (bid&7). 128 consecutive
    // works per XCD = 4 (b,h) pairs; K+V = 2MB per XCD -> L2-resident.
    const int bid  = blockIdx.x;                   // 0..1023
    const int work = ((bid & 7) << 7) | (bid >> 3);
    const int q0 = (work & 31) * 64;
    const int h  = (work >> 5) & 15;
    const int b  = work >> 9;

    const int t    = threadIdx.x;
    const int lane = t & 63;
    const int w    = t >> 6;
    const int lo   = lane & 15;
    const int g    = lane >> 4;

    __shared__ bf16_t QPs[64 * 72];   // Q tile; re-used as per-wave P strips
    __shared__ bf16_t Ks [64 * 72];
    __shared__ bf16_t VTs[64 * 72];   // V^T, XOR-swizzled (s' = s ^ (d&56))
    __shared__ float  Ms [S_];        // mask row for this batch (8KB)

    const bf16_t* qg = qbuf + ((size_t)(b * NH_ + h) * S_ + q0) * HD_;
    const bf16_t* kg = kbuf + (size_t)(b * NH_ + h) * S_ * HD_;
    const bf16_t* vg = vbuf + (size_t)(b * NH_ + h) * S_ * HD_;
    const float*  relg  = rel + ((size_t)((b * NH_ + h) * S_ + q0)) * S_;
    const float*  maskg = mask + (size_t)b * S_;

    // per-thread staging slot: rows r0, r0+32; cols c8..c8+7
    const int r0 = t >> 3;            // 0..31
    const int c8 = (t & 7) * 8;

    // ---- prologue: issue chunk-0 K/V loads first (deepest prefetch),
    // then Q + mask loads, then rel(0) prefetch.
    uint4 kv0 = *(const uint4*)&kg[(size_t)r0 * 64 + c8];
    uint4 kv1 = *(const uint4*)&kg[(size_t)(r0 + 32) * 64 + c8];
    uint4 vv0 = *(const uint4*)&vg[(size_t)r0 * 64 + c8];
    uint4 vv1 = *(const uint4*)&vg[(size_t)(r0 + 32) * 64 + c8];

    uint4  qv0 = *(const uint4*)&qg[(size_t)r0 * 64 + c8];
    uint4  qv1 = *(const uint4*)&qg[(size_t)(r0 + 32) * 64 + c8];
    float4 mv0 = *(const float4*)&maskg[t * 8];
    float4 mv1 = *(const float4*)&maskg[t * 8 + 4];

    const int qrow = w * 16 + g * 4;  // +r
    float rl[4][4];
#pragma unroll
    for (int r = 0; r < 4; ++r)
#pragma unroll
        for (int nt = 0; nt < 4; ++nt)
            rl[r][nt] = relg[(size_t)(qrow + r) * S_ + nt * 16 + lo];

    *(uint4*)&QPs[r0 * 72 + c8]        = qv0;
    *(uint4*)&QPs[(r0 + 32) * 72 + c8] = qv1;
    *(float4*)&Ms[t * 8]     = mv0;
    *(float4*)&Ms[t * 8 + 4] = mv1;

    asm volatile("s_waitcnt lgkmcnt(0)" ::: "memory");
    __builtin_amdgcn_s_barrier();

    // Q A-frags (q pre-scaled by 1/8 in the GEMM). Wave-private rows: each
    // wave later overwrites only its own strip of QPs, which only it read.
    bf16x8 aq0 = *(const bf16x8*)&QPs[(w * 16 + lo) * 72 + g * 8];
    bf16x8 aq1 = *(const bf16x8*)&QPs[(w * 16 + lo) * 72 + g * 8 + 32];

    float mi[4], li[4];
    f32x4 accO[4];
#pragma unroll
    for (int r = 0; r < 4; ++r) { mi[r] = -1e30f; li[r] = 0.f; }
#pragma unroll
    for (int dt = 0; dt < 4; ++dt) accO[dt] = (f32x4){0.f, 0.f, 0.f, 0.f};

    for (int kc = 0; kc < 32; ++kc) {
        // [write phase] prev chunk's LDS reads done (bottom barrier).
        // Compiler inserts counted vmcnt waits for kv/vv regs here.
        *(uint4*)&Ks[r0 * 72 + c8]        = kv0;
        *(uint4*)&Ks[(r0 + 32) * 72 + c8] = kv1;
        {
            const bf16_t* vp0 = (const bf16_t*)&vv0;
            const bf16_t* vp1 = (const bf16_t*)&vv1;
            int sw0 = r0 ^ c8, sw1 = (r0 + 32) ^ c8;
#pragma unroll
            for (int j = 0; j < 8; ++j) {
                VTs[(c8 + j) * 72 + sw0] = vp0[j];
                VTs[(c8 + j) * 72 + sw1] = vp1[j];
            }
        }
        // issue next chunk's K/V loads; they stay in flight across the
        // barrier and the whole compute phase (clamped reload on last iter).
        {
            const int kn = (kc < 31) ? kc + 1 : kc;
            const bf16_t* kgn = kg + (size_t)kn * 64 * 64;
            const bf16_t* vgn = vg + (size_t)kn * 64 * 64;
            kv0 = *(const uint4*)&kgn[(size_t)r0 * 64 + c8];
            kv1 = *(const uint4*)&kgn[(size_t)(r0 + 32) * 64 + c8];
            vv0 = *(const uint4*)&vgn[(size_t)r0 * 64 + c8];
            vv1 = *(const uint4*)&vgn[(size_t)(r0 + 32) * 64 + c8];
        }

        asm volatile("s_waitcnt lgkmcnt(0)" ::: "memory");  // drain ds_writes
        __builtin_amdgcn_s_barrier();                       // tile visible

        // [QK phase]
        f32x4 sc[4];
        __builtin_amdgcn_s_setprio(1);
#pragma unroll
        for (int nt = 0; nt < 4; ++nt) {
            bf16x8 b0 = *(const bf16x8*)&Ks[(nt * 16 + lo) * 72 + g * 8];
            bf16x8 b1 = *(const bf16x8*)&Ks[(nt * 16 + lo) * 72 + g * 8 + 32];
            f32x4 z = (f32x4){0.f, 0.f, 0.f, 0.f};
            z = __builtin_amdgcn_mfma_f32_16x16x32_bf16(aq0, b0, z, 0, 0, 0);
            z = __builtin_amdgcn_mfma_f32_16x16x32_bf16(aq1, b1, z, 0, 0, 0);
            sc[nt] = z;
        }
        __builtin_amdgcn_s_setprio(0);

        // scores = qk + mask(LDS) + rel (prefetched)
        float sv[4][4];
#pragma unroll
        for (int nt = 0; nt < 4; ++nt) {
            float mk = Ms[kc * 64 + nt * 16 + lo];
#pragma unroll
            for (int r = 0; r < 4; ++r)
                sv[r][nt] = sc[nt][r] + mk + rl[r][nt];
        }

        // issue next chunk's rel loads (hidden under softmax + PV)
        if (kc < 31) {
#pragma unroll
            for (int r = 0; r < 4; ++r)
#pragma unroll
                for (int nt = 0; nt < 4; ++nt)
                    rl[r][nt] = relg[(size_t)(qrow + r) * S_ + (kc + 1) * 64 + nt * 16 + lo];
        }

        // online softmax; P into this wave's swizzled strip
        bf16_t* Pw = &QPs[w * 16 * 72];
#pragma unroll
        for (int r = 0; r < 4; ++r) {
            float vmax = fmaxf(fmaxf(sv[r][0], sv[r][1]), fmaxf(sv[r][2], sv[r][3]));
#pragma unroll
            for (int mk2 = 1; mk2 < 16; mk2 <<= 1)
                vmax = fmaxf(vmax, __shfl_xor(vmax, mk2, 16));
            float mnew  = fmaxf(mi[r], vmax);
            float alpha = __expf(mi[r] - mnew);
            float rsum = 0.f;
#pragma unroll
            for (int nt = 0; nt < 4; ++nt) {
                float p = __expf(sv[r][nt] - mnew);
                sv[r][nt] = p;
                rsum += p;
            }
#pragma unroll
            for (int mk2 = 1; mk2 < 16; mk2 <<= 1)
                rsum += __shfl_xor(rsum, mk2, 16);
            li[r] = li[r] * alpha + rsum;
            mi[r] = mnew;
#pragma unroll
            for (int dt = 0; dt < 4; ++dt) accO[dt][r] *= alpha;
#pragma unroll
            for (int nt = 0; nt < 4; ++nt)
                Pw[(g * 4 + r) * 72 + ((nt * 16 + lo) ^ (g * 8))] = (bf16_t)sv[r][nt];
        }
        // no barrier: P strip is wave-private; in-wave ds order via lgkmcnt.

        // [PV phase]
        bf16x8 pa0 = *(const bf16x8*)&Pw[lo * 72 + ((g * 8)       ^ ((lo >> 2) * 8))];
        bf16x8 pa1 = *(const bf16x8*)&Pw[lo * 72 + (((4 + g) * 8) ^ ((lo >> 2) * 8))];
        __builtin_amdgcn_s_setprio(1);
#pragma unroll
        for (int dt = 0; dt < 4; ++dt) {
            int d = dt * 16 + lo;
            bf16x8 v0 = *(const bf16x8*)&VTs[d * 72 + ((g * 8)       ^ (d & 56))];
            bf16x8 v1 = *(const bf16x8*)&VTs[d * 72 + (((4 + g) * 8) ^ (d & 56))];
            accO[dt] = __builtin_amdgcn_mfma_f32_16x16x32_bf16(pa0, v0, accO[dt], 0, 0, 0);
            accO[dt] = __builtin_amdgcn_mfma_f32_16x16x32_bf16(pa1, v1, accO[dt], 0, 0, 0);
        }
        __builtin_amdgcn_s_setprio(0);

        // all in-wave LDS reads retired (compiler lgkmcnt before MFMA use);
        // barrier before next chunk overwrites Ks/VTs.
        __builtin_amdgcn_s_barrier();
    }

    // epilogue: out[b][s][h*64+d] = O / l
#pragma unroll
    for (int dt = 0; dt < 4; ++dt) {
        int d = dt * 16 + lo;
#pragma unroll
        for (int r = 0; r < 4; ++r) {
            int row = q0 + w * 16 + g * 4 + r;
            out[((size_t)(b * S_ + row)) * H_ + h * HD_ + d] = accO[dt][r] / li[r];
        }
    }
}

extern "C" void kernel_launch(void* const* d_in, const int* in_sizes, int n_in,
                              void* d_out, int out_size, void* d_ws, size_t ws_size,
                              hipStream_t stream) {
    const float* hs   = (const float*)d_in[0];
    const float* mask = (const float*)d_in[1];
    const float* rel  = (const float*)d_in[2];
    const float* Wq   = (const float*)d_in[3];
    const float* bq   = (const float*)d_in[4];
    const float* Wk   = (const float*)d_in[5];
    const float* bk   = (const float*)d_in[6];
    const float* Wv   = (const float*)d_in[7];
    const float* bv   = (const float*)d_in[8];
    float* out = (float*)d_out;

    const size_t qkv_elems = (size_t)B_ * NH_ * S_ * HD_;  // 4,194,304
    bf16_t* qbuf = (bf16_t*)d_ws;
    bf16_t* kbuf = qbuf + qkv_elems;
    bf16_t* vbuf = kbuf + qkv_elems;
    bf16_t* Xb   = vbuf + qkv_elems;               // 4M elems
    bf16_t* Wb   = Xb   + qkv_elems;               // 3M elems (Wq,Wk,Wv)

    cast_bf16<<<7168, 256, 0, stream>>>(hs, Wq, Wk, Wv, Xb, Wb);
    qkv_gemm<<<dim3(32, 8, 3), 256, 0, stream>>>(Xb, Wb, bq, bk, bv,
                                                 qbuf, kbuf, vbuf);
    attn<<<1024, 256, 0, stream>>>(qbuf, kbuf, vbuf, mask, rel, out);
}